// Round 16
// baseline (144.323 us; speedup 1.0000x reference)
//
#include <hip/hip_runtime.h>
#include <hip/hip_bf16.h>
#include <stdint.h>

// ---------------- problem constants ----------------
#define PDIM   1024
#define HEADS  16
#define DHEAD  64
#define BATCH  2
#define SEQ    2048
#define ROWS   (BATCH*SEQ)     // 4096
#define NBH    (BATCH*HEADS)   // 32

typedef __attribute__((ext_vector_type(8))) short s8v;     // 8 x bf16 (4 VGPR)
typedef __attribute__((ext_vector_type(4))) float f32x4;   // 16x16 MFMA accum
typedef __attribute__((ext_vector_type(16))) float f32x16; // 32x32 MFMA accum
typedef unsigned short ushort_t;
typedef unsigned int   uint32;

// Q pre-scale: DIM_HEAD^-0.5 * log2(e)  (folded into Wqt prep, Q columns)
#define QSCALE 0.18033688011112042f
// fixed softmax bias (log2 units): p = exp2(s - MFIX); cancels in num/denom
#define MFIX 12.0f

// ---------------- helpers ----------------
__device__ __forceinline__ ushort_t f2bf(float x){
  union { float f; uint32 u; } v; v.f = x;
  uint32 r = v.u + 0x7FFFu + ((v.u >> 16) & 1u);   // RTN-even
  return (ushort_t)(r >> 16);
}
__device__ __forceinline__ uint32 cvt_pk_bf16(float lo, float hi){
  uint32 r;
  asm("v_cvt_pk_bf16_f32 %0, %1, %2" : "=v"(r) : "v"(lo), "v"(hi));
  return r;   // bf16(lo) in [15:0], bf16(hi) in [31:16]
}

typedef const __attribute__((address_space(1))) void* gas_ptr;
typedef __attribute__((address_space(3))) void*       las_ptr;
__device__ __forceinline__ void g2l16(const void* g, void* l){
  // dest = wave-uniform LDS base; HW adds lane*16
  __builtin_amdgcn_global_load_lds((gas_ptr)g, (las_ptr)l, 16, 0, 0);
}

// ---------------- fused prep: x cvt + w_qkv tcvt (Q-cols pre-scaled) + w_out tcvt ----------------
__global__ __launch_bounds__(256) void k_prep(
    const float* __restrict__ x, const float* __restrict__ w_qkv,
    const float* __restrict__ w_out,
    ushort_t* __restrict__ Xh, ushort_t* __restrict__ Wqt_h,
    ushort_t* __restrict__ Wot_h){
  __shared__ float tile[64][65];
  const int bid = blockIdx.x;
  if (bid < 4096){
    int i = bid * 256 + threadIdx.x;
    float4 v = reinterpret_cast<const float4*>(x)[i];
    reinterpret_cast<ushort4*>(Xh)[i] =
        make_ushort4(f2bf(v.x), f2bf(v.y), f2bf(v.z), f2bf(v.w));
    return;
  }
  const float* src; ushort_t* dst; int R, C, cb, rb;
  float scl = 1.f;
  if (bid < 4864){
    int t = bid - 4096; src = w_qkv; dst = Wqt_h; R = 1024; C = 3072;
    cb = (t % 48) * 64; rb = (t / 48) * 64;
    if (cb < 1024) scl = QSCALE;          // Q columns: fold DIM_HEAD^-0.5*log2(e)
  } else {
    int t = bid - 4864; src = w_out; dst = Wot_h; R = 1024; C = 1024;
    cb = (t % 16) * 64; rb = (t / 16) * 64;
  }
  int t = threadIdx.x;
  int lw = t >> 6, lc = t & 63;
#pragma unroll
  for (int i = 0; i < 16; i++){
    int r = i * 4 + lw;
    tile[r][lc] = src[(size_t)(rb + r) * C + cb + lc];
  }
  __syncthreads();
#pragma unroll
  for (int i = 0; i < 16; i++){
    int c = i * 4 + lw;
    dst[(size_t)(cb + c) * R + rb + lc] = f2bf(tile[lc][c] * scl);
  }
}

// ---------------- GEMM core (128x128 tile, BK=64, 4 waves, dbuf + swizzle) ----------------
#define GBM 128
#define GBN 128
#define GBK 64

// ---------------- QKV projection GEMM, fused per-head epilogue ----------------
__global__ __launch_bounds__(256, 3) void k_gemm_qkv(
    const ushort_t* __restrict__ Xh, const ushort_t* __restrict__ Wqt_h,
    ushort_t* __restrict__ Qh, ushort_t* __restrict__ Kh, ushort_t* __restrict__ Vth){
  __shared__ __align__(16) ushort_t Asm[2][GBM * GBK];
  __shared__ __align__(16) ushort_t Bsm[2][GBM * GBK];
  const int tid  = threadIdx.x;
  const int wave = tid >> 6, lane = tid & 63;
  const int mb = blockIdx.y * GBM, nb = blockIdx.x * GBN;
  const int wr = wave >> 1, wc = wave & 1;
  const int l15 = lane & 15, l4 = lane >> 4;
  const int rsub = lane >> 3;
  const int schunk = ((lane & 7) ^ rsub) * 8;  // source-swizzled chunk
  f32x4 acc[4][4] = {};

  auto stage = [&](int buf, int kb){
    int k0 = kb * GBK;
#pragma unroll
    for (int i = 0; i < 4; i++){
      int row = (i * 4 + wave) * 8 + rsub;
      g2l16(Xh    + (size_t)(mb + row) * 1024 + k0 + schunk, &Asm[buf][(i * 4 + wave) * 512]);
      g2l16(Wqt_h + (size_t)(nb + row) * 1024 + k0 + schunk, &Bsm[buf][(i * 4 + wave) * 512]);
    }
  };

  stage(0, 0);

  for (int kb = 0; kb < 16; kb++){
    const int cur = kb & 1;
    if (kb < 15){
      stage(cur ^ 1, kb + 1);
      asm volatile("s_waitcnt vmcnt(8)" ::: "memory");
    } else {
      asm volatile("s_waitcnt vmcnt(0)" ::: "memory");
    }
    __builtin_amdgcn_s_barrier();
    __builtin_amdgcn_s_setprio(1);
#pragma unroll
    for (int ks = 0; ks < 2; ks++){
      s8v af[4], bfr[4];
#pragma unroll
      for (int f = 0; f < 4; f++){
        int ch = (((ks * 4 + l4) ^ (l15 & 7)) << 3);
        af[f]  = *reinterpret_cast<const s8v*>(&Asm[cur][(wr * 64 + f * 16 + l15) * 64 + ch]);
        bfr[f] = *reinterpret_cast<const s8v*>(&Bsm[cur][(wc * 64 + f * 16 + l15) * 64 + ch]);
      }
#pragma unroll
      for (int fr = 0; fr < 4; fr++)
#pragma unroll
        for (int fc = 0; fc < 4; fc++)
          acc[fr][fc] = __builtin_amdgcn_mfma_f32_16x16x32_bf16(af[fr], bfr[fc], acc[fr][fc], 0, 0, 0);
    }
    __builtin_amdgcn_s_setprio(0);
    __builtin_amdgcn_s_barrier();
  }

  // fused epilogue: cols [nb,nb+128) all in one part (1024 % 128 == 0)
  const int pnum = nb >> 10;
#pragma unroll
  for (int fr = 0; fr < 4; fr++){
    int row  = mb + wr * 64 + fr * 16 + l4 * 4;
    int b    = row >> 11;
    int nseq = row & 2047;
#pragma unroll
    for (int fc = 0; fc < 4; fc++){
      int col = nb + wc * 64 + fc * 16 + l15;
      int rem = col & 1023;
      int h = rem >> 6, d = rem & 63;
      int bh = b * 16 + h;
      if (pnum == 0){          // Q (scale pre-folded into W)
        size_t base = ((size_t)bh * SEQ + nseq) * 64 + d;
#pragma unroll
        for (int r = 0; r < 4; r++)
          Qh[base + (size_t)r * 64] = f2bf(acc[fr][fc][r]);
      } else if (pnum == 1){   // K
        size_t base = ((size_t)bh * SEQ + nseq) * 64 + d;
#pragma unroll
        for (int r = 0; r < 4; r++)
          Kh[base + (size_t)r * 64] = f2bf(acc[fr][fc][r]);
      } else {                 // V: transposed [bh][d][SEQ]
        size_t base = ((size_t)bh * 64 + d) * SEQ + nseq;
        *reinterpret_cast<ushort4*>(&Vth[base]) =
            make_ushort4(f2bf(acc[fr][fc][0]), f2bf(acc[fr][fc][1]),
                         f2bf(acc[fr][fc][2]), f2bf(acc[fr][fc][3]));
      }
    }
  }
}

// ---------------- out-projection GEMM (plain bf16, dbuf + swizzle) ----------------
__global__ __launch_bounds__(256, 2) void k_gemm_out(
    const ushort_t* __restrict__ Ah, const ushort_t* __restrict__ Bth,
    float* __restrict__ C, const float* __restrict__ bias){
  __shared__ __align__(16) ushort_t Asm[2][GBM * GBK];
  __shared__ __align__(16) ushort_t Bsm[2][GBM * GBK];
  const int tid  = threadIdx.x;
  const int wave = tid >> 6, lane = tid & 63;
  const int mb = blockIdx.y * GBM, nb = blockIdx.x * GBN;
  const int wr = wave >> 1, wc = wave & 1;
  const int l15 = lane & 15, l4 = lane >> 4;
  const int rsub = lane >> 3;
  const int schunk = ((lane & 7) ^ rsub) * 8;
  f32x4 acc[4][4] = {};

  auto stage = [&](int buf, int kb){
    int k0 = kb * GBK;
#pragma unroll
    for (int i = 0; i < 4; i++){
      int row = (i * 4 + wave) * 8 + rsub;
      g2l16(Ah  + (size_t)(mb + row) * 1024 + k0 + schunk, &Asm[buf][(i * 4 + wave) * 512]);
      g2l16(Bth + (size_t)(nb + row) * 1024 + k0 + schunk, &Bsm[buf][(i * 4 + wave) * 512]);
    }
  };

  stage(0, 0);

  for (int kb = 0; kb < 16; kb++){
    const int cur = kb & 1;
    if (kb < 15){
      stage(cur ^ 1, kb + 1);
      asm volatile("s_waitcnt vmcnt(8)" ::: "memory");
    } else {
      asm volatile("s_waitcnt vmcnt(0)" ::: "memory");
    }
    __builtin_amdgcn_s_barrier();
    __builtin_amdgcn_s_setprio(1);
#pragma unroll
    for (int ks = 0; ks < 2; ks++){
      s8v af[4], bfr[4];
#pragma unroll
      for (int f = 0; f < 4; f++){
        int ch = (((ks * 4 + l4) ^ (l15 & 7)) << 3);
        af[f]  = *reinterpret_cast<const s8v*>(&Asm[cur][(wr * 64 + f * 16 + l15) * 64 + ch]);
        bfr[f] = *reinterpret_cast<const s8v*>(&Bsm[cur][(wc * 64 + f * 16 + l15) * 64 + ch]);
      }
#pragma unroll
      for (int fr = 0; fr < 4; fr++)
#pragma unroll
        for (int fc = 0; fc < 4; fc++)
          acc[fr][fc] = __builtin_amdgcn_mfma_f32_16x16x32_bf16(af[fr], bfr[fc], acc[fr][fc], 0, 0, 0);
    }
    __builtin_amdgcn_s_setprio(0);
    __builtin_amdgcn_s_barrier();
  }
#pragma unroll
  for (int fr = 0; fr < 4; fr++){
    int row = mb + wr * 64 + fr * 16 + l4 * 4;
#pragma unroll
    for (int fc = 0; fc < 4; fc++){
      int col = nb + wc * 64 + fc * 16 + l15;
      float bv = bias[col];
#pragma unroll
      for (int r = 0; r < 4; r++)
        C[(size_t)(row + r) * 1024 + col] = acc[fr][fc][r] + bv;
    }
  }
}

// ---------------- flash attention (2x fragment reuse: 64 q/wave, 2-wave blocks) ----------------
// Grid 512 x 128 thr (2 waves x 64 q = 128 q/block); LDS 32KB (K+V dbuf) -> up to
// 4 blocks/CU. KEY CHANGE vs r12: each wave owns TWO q-groups of 32, so every
// K/V fragment ds_read feeds 2 MFMAs -> 16 ds_read per 32 MFMA (halves the
// LDS-read throughput demand that dominates the cycle budget). Math identical to
// r12 (verified): swapped 32x32 QK -> C[kv][q]; in-register P via cvt_pk +
// v_permlane32_swap; fixed-max softmax; direct bf16 Ah write (no split/combine).
__global__ __launch_bounds__(128, 2) void k_flash(
    const ushort_t* __restrict__ Qh, const ushort_t* __restrict__ Kh,
    const ushort_t* __restrict__ Vth, ushort_t* __restrict__ Ah){
  __shared__ __align__(16) ushort_t KhS[2][64 * 64];   // [kv][d]
  __shared__ __align__(16) ushort_t VhS[2][64 * 64];   // [d][kv]
  const int lid = blockIdx.x;             // 0..511
  const int xcd = lid & 7, g = lid >> 3;  // 8 XCDs x 64 blocks
  const int bh = xcd * 4 + (g & 3);       // each XCD owns 4 heads (K/V L2-resident)
  const int qb = (g >> 2) * 128;          // 16 q-tiles of 128
  const int tid = threadIdx.x, wave = tid >> 6, lane = tid & 63;
  const int l31 = lane & 31, hh = lane >> 5;
  const int b = bh >> 4, hd = bh & 15;
  const size_t hbase = (size_t)bh * SEQ * 64;
  const int rsub = lane >> 3;             // 0..7
  const int schunk = ((lane & 7) ^ rsub) * 8;

  // frag-read element offsets: row l31, chunk (2s+hh) ^ (l31&7)
  int fch[4];
#pragma unroll
  for (int s = 0; s < 4; s++)
    fch[s] = (((2 * s + hh) ^ (l31 & 7)) << 3);
  const int fbase = l31 * 64;

  // Q as B-operand frags, 2 q-groups of 32 per wave
  s8v qf[2][4];
#pragma unroll
  for (int grp = 0; grp < 2; grp++)
#pragma unroll
    for (int s = 0; s < 4; s++)
      qf[grp][s] = *reinterpret_cast<const s8v*>(
          &Qh[hbase + (size_t)(qb + wave * 64 + grp * 32 + l31) * 64 + s * 16 + hh * 8]);

  const f32x16 fzero = {};
  f32x16 o[2][2] = {};             // [grp][d-block]
  float lsum[2] = {0.f, 0.f};

  auto stage = [&](int buf, int kt){   // 2-wave staging: 8 loads/wave
    int kvb = kt * 64;
#pragma unroll
    for (int i = 0; i < 4; i++){
      int row = (i * 2 + wave) * 8 + rsub;
      g2l16(Kh  + hbase + (size_t)(kvb + row) * 64 + schunk, &KhS[buf][(i * 2 + wave) * 512]);
      g2l16(Vth + ((size_t)bh * 64 + row) * SEQ + kvb + schunk, &VhS[buf][(i * 2 + wave) * 512]);
    }
  };

  stage(0, 0);

  for (int kt = 0; kt < 32; kt++){
    const int cur = kt & 1;
    if (kt < 31){
      stage(cur ^ 1, kt + 1);                          // next tile's 8 loads in flight
      asm volatile("s_waitcnt vmcnt(8)" ::: "memory"); // current tile's 8 landed
    } else {
      asm volatile("s_waitcnt vmcnt(0)" ::: "memory");
    }
    __builtin_amdgcn_s_barrier();

    // QK: C[kv][q] for 2 kv-blocks x 2 q-groups; each kf feeds 2 MFMAs
    f32x16 s00 = fzero, s01 = fzero, s10 = fzero, s11 = fzero;
    __builtin_amdgcn_s_setprio(1);
#pragma unroll
    for (int s = 0; s < 4; s++){
      s8v kf0 = *reinterpret_cast<const s8v*>(&KhS[cur][fbase + fch[s]]);
      s8v kf1 = *reinterpret_cast<const s8v*>(&KhS[cur][fbase + 2048 + fch[s]]);
      s00 = __builtin_amdgcn_mfma_f32_32x32x16_bf16(kf0, qf[0][s], s00, 0, 0, 0);
      s01 = __builtin_amdgcn_mfma_f32_32x32x16_bf16(kf1, qf[0][s], s01, 0, 0, 0);
      s10 = __builtin_amdgcn_mfma_f32_32x32x16_bf16(kf0, qf[1][s], s10, 0, 0, 0);
      s11 = __builtin_amdgcn_mfma_f32_32x32x16_bf16(kf1, qf[1][s], s11, 0, 0, 0);
    }
    __builtin_amdgcn_s_setprio(0);

    // fixed-max softmax + pack: w[grp][rb][t]
    uint32 w[2][2][8];
#pragma unroll
    for (int t = 0; t < 8; t++){
      float a0 = __builtin_amdgcn_exp2f(s00[2 * t]     - MFIX);
      float b0 = __builtin_amdgcn_exp2f(s00[2 * t + 1] - MFIX);
      float a1 = __builtin_amdgcn_exp2f(s01[2 * t]     - MFIX);
      float b1 = __builtin_amdgcn_exp2f(s01[2 * t + 1] - MFIX);
      lsum[0] += (a0 + b0) + (a1 + b1);
      w[0][0][t] = cvt_pk_bf16(a0, b0);
      w[0][1][t] = cvt_pk_bf16(a1, b1);
      float a2 = __builtin_amdgcn_exp2f(s10[2 * t]     - MFIX);
      float b2 = __builtin_amdgcn_exp2f(s10[2 * t + 1] - MFIX);
      float a3 = __builtin_amdgcn_exp2f(s11[2 * t]     - MFIX);
      float b3 = __builtin_amdgcn_exp2f(s11[2 * t + 1] - MFIX);
      lsum[1] += (a2 + b2) + (a3 + b3);
      w[1][0][t] = cvt_pk_bf16(a2, b2);
      w[1][1][t] = cvt_pk_bf16(a3, b3);
    }

    // PV: each vf feeds 2 MFMAs (both groups); P frags via permlane swaps
    __builtin_amdgcn_s_setprio(1);
#pragma unroll
    for (int st = 0; st < 4; st++){
      const int rb = st >> 1, u = (st & 1) * 4;
      s8v vf0 = *reinterpret_cast<const s8v*>(&VhS[cur][fbase + fch[st]]);
      s8v vf1 = *reinterpret_cast<const s8v*>(&VhS[cur][fbase + 2048 + fch[st]]);
#pragma unroll
      for (int grp = 0; grp < 2; grp++){
        uint32 m0 = w[grp][rb][u],     m2 = w[grp][rb][u + 2];
        uint32 m1 = w[grp][rb][u + 1], m3 = w[grp][rb][u + 3];
        asm("v_permlane32_swap_b32 %0, %1" : "+v"(m0), "+v"(m2));
        asm("v_permlane32_swap_b32 %0, %1" : "+v"(m1), "+v"(m3));
        union { uint32 u4[4]; s8v v; } pf;
        pf.u4[0] = m0; pf.u4[1] = m1; pf.u4[2] = m2; pf.u4[3] = m3;
        o[grp][0] = __builtin_amdgcn_mfma_f32_32x32x16_bf16(pf.v, vf0, o[grp][0], 0, 0, 0);
        o[grp][1] = __builtin_amdgcn_mfma_f32_32x32x16_bf16(pf.v, vf1, o[grp][1], 0, 0, 0);
      }
    }
    __builtin_amdgcn_s_setprio(0);
    __builtin_amdgcn_s_barrier();   // both waves done reading cur buffers
  }

  // epilogue: per group, lane holds lsum-half for q=l31; combine, per-reg shfl
#pragma unroll
  for (int grp = 0; grp < 2; grp++){
    float ls = lsum[grp] + __shfl_xor(lsum[grp], 32);
    float linv = 1.f / ls;
#pragma unroll
    for (int r = 0; r < 16; r++){
      int q = (r & 3) + 8 * (r >> 2) + 4 * hh;
      float sc = __shfl(linv, q);
      int n = qb + wave * 64 + grp * 32 + q;
      size_t rowb = (size_t)(b * SEQ + n) * 1024 + hd * 64;
      Ah[rowb + l31]      = f2bf(o[grp][0][r] * sc);
      Ah[rowb + 32 + l31] = f2bf(o[grp][1][r] * sc);
    }
  }
}

// ---------------- host launch ----------------
extern "C" void kernel_launch(void* const* d_in, const int* in_sizes, int n_in,
                              void* d_out, int out_size, void* d_ws, size_t ws_size,
                              hipStream_t stream){
  const float* x     = (const float*)d_in[0];
  const float* w_qkv = (const float*)d_in[1];
  const float* w_out = (const float*)d_in[2];
  const float* b_out = (const float*)d_in[3];
  float* out = (float*)d_out;
  char* ws = (char*)d_ws;

  ushort_t* Xh    = (ushort_t*)(ws);                      //  8 MB
  ushort_t* Wqt_h = (ushort_t*)(ws + 8388608);            //  6 MB
  ushort_t* Wot_h = (ushort_t*)(ws + 14680064);           //  2 MB
  ushort_t* Qh    = (ushort_t*)(ws + 16777216);           //  8 MB
  ushort_t* Kh    = (ushort_t*)(ws + 25165824);           //  8 MB
  ushort_t* Vth   = (ushort_t*)(ws + 33554432);           //  8 MB
  ushort_t* Ah    = (ushort_t*)(ws + 41943040);           //  8 MB

  // 1. fused prep: x -> Xh; w_qkv -> Wqt_h (T, Q cols pre-scaled); w_out -> Wot_h (T)
  k_prep<<<5120, 256, 0, stream>>>(x, w_qkv, w_out, Xh, Wqt_h, Wot_h);
  // 2. QKV projection with fused per-head epilogue
  k_gemm_qkv<<<dim3(24, 32), 256, 0, stream>>>(Xh, Wqt_h, Qh, Kh, Vth);
  // 3. attention -> Ah (bf16), 2x fragment reuse
  k_flash<<<512, 128, 0, stream>>>(Qh, Kh, Vth, Ah);
  // 4. out = Ah @ Wot + b_out
  k_gemm_out<<<dim3(8, 32), 256, 0, stream>>>(Ah, Wot_h, out, b_out);
}

// Round 17
// 116.328 us; speedup vs baseline: 1.2407x; 1.2407x over previous
//
#include <hip/hip_runtime.h>
#include <hip/hip_bf16.h>
#include <stdint.h>

// ---------------- problem constants ----------------
#define PDIM   1024
#define HEADS  16
#define DHEAD  64
#define BATCH  2
#define SEQ    2048
#define ROWS   (BATCH*SEQ)     // 4096
#define NBH    (BATCH*HEADS)   // 32

typedef __attribute__((ext_vector_type(8))) short s8v;     // 8 x bf16 (4 VGPR)
typedef __attribute__((ext_vector_type(4))) float f32x4;   // 16x16 MFMA accum
typedef __attribute__((ext_vector_type(16))) float f32x16; // 32x32 MFMA accum
typedef unsigned short ushort_t;
typedef unsigned int   uint32;

// Q pre-scale: DIM_HEAD^-0.5 * log2(e)  (folded into Wqt prep, Q columns)
#define QSCALE 0.18033688011112042f
// fixed softmax bias (log2 units): p = exp2(s - MFIX); cancels in num/denom
#define MFIX 12.0f

// ---------------- helpers ----------------
__device__ __forceinline__ ushort_t f2bf(float x){
  union { float f; uint32 u; } v; v.f = x;
  uint32 r = v.u + 0x7FFFu + ((v.u >> 16) & 1u);   // RTN-even
  return (ushort_t)(r >> 16);
}
__device__ __forceinline__ uint32 cvt_pk_bf16(float lo, float hi){
  uint32 r;
  asm("v_cvt_pk_bf16_f32 %0, %1, %2" : "=v"(r) : "v"(lo), "v"(hi));
  return r;   // bf16(lo) in [15:0], bf16(hi) in [31:16]
}

typedef const __attribute__((address_space(1))) void* gas_ptr;
typedef __attribute__((address_space(3))) void*       las_ptr;
__device__ __forceinline__ void g2l16(const void* g, void* l){
  // dest = wave-uniform LDS base; HW adds lane*16
  __builtin_amdgcn_global_load_lds((gas_ptr)g, (las_ptr)l, 16, 0, 0);
}

// ---------------- fused prep: x cvt + w_qkv tcvt (Q-cols pre-scaled) + w_out tcvt ----------------
__global__ __launch_bounds__(256) void k_prep(
    const float* __restrict__ x, const float* __restrict__ w_qkv,
    const float* __restrict__ w_out,
    ushort_t* __restrict__ Xh, ushort_t* __restrict__ Wqt_h,
    ushort_t* __restrict__ Wot_h){
  __shared__ float tile[64][65];
  const int bid = blockIdx.x;
  if (bid < 4096){
    int i = bid * 256 + threadIdx.x;
    float4 v = reinterpret_cast<const float4*>(x)[i];
    reinterpret_cast<ushort4*>(Xh)[i] =
        make_ushort4(f2bf(v.x), f2bf(v.y), f2bf(v.z), f2bf(v.w));
    return;
  }
  const float* src; ushort_t* dst; int R, C, cb, rb;
  float scl = 1.f;
  if (bid < 4864){
    int t = bid - 4096; src = w_qkv; dst = Wqt_h; R = 1024; C = 3072;
    cb = (t % 48) * 64; rb = (t / 48) * 64;
    if (cb < 1024) scl = QSCALE;          // Q columns: fold DIM_HEAD^-0.5*log2(e)
  } else {
    int t = bid - 4864; src = w_out; dst = Wot_h; R = 1024; C = 1024;
    cb = (t % 16) * 64; rb = (t / 16) * 64;
  }
  int t = threadIdx.x;
  int lw = t >> 6, lc = t & 63;
#pragma unroll
  for (int i = 0; i < 16; i++){
    int r = i * 4 + lw;
    tile[r][lc] = src[(size_t)(rb + r) * C + cb + lc];
  }
  __syncthreads();
#pragma unroll
  for (int i = 0; i < 16; i++){
    int c = i * 4 + lw;
    dst[(size_t)(cb + c) * R + rb + lc] = f2bf(tile[lc][c] * scl);
  }
}

// ---------------- GEMM core (128x128 tile, BK=64, 4 waves, dbuf + swizzle) ----------------
#define GBM 128
#define GBN 128
#define GBK 64

// ---------------- QKV projection GEMM, fused per-head epilogue ----------------
__global__ __launch_bounds__(256, 3) void k_gemm_qkv(
    const ushort_t* __restrict__ Xh, const ushort_t* __restrict__ Wqt_h,
    ushort_t* __restrict__ Qh, ushort_t* __restrict__ Kh, ushort_t* __restrict__ Vth){
  __shared__ __align__(16) ushort_t Asm[2][GBM * GBK];
  __shared__ __align__(16) ushort_t Bsm[2][GBM * GBK];
  const int tid  = threadIdx.x;
  const int wave = tid >> 6, lane = tid & 63;
  const int mb = blockIdx.y * GBM, nb = blockIdx.x * GBN;
  const int wr = wave >> 1, wc = wave & 1;
  const int l15 = lane & 15, l4 = lane >> 4;
  const int rsub = lane >> 3;
  const int schunk = ((lane & 7) ^ rsub) * 8;  // source-swizzled chunk
  f32x4 acc[4][4] = {};

  auto stage = [&](int buf, int kb){
    int k0 = kb * GBK;
#pragma unroll
    for (int i = 0; i < 4; i++){
      int row = (i * 4 + wave) * 8 + rsub;
      g2l16(Xh    + (size_t)(mb + row) * 1024 + k0 + schunk, &Asm[buf][(i * 4 + wave) * 512]);
      g2l16(Wqt_h + (size_t)(nb + row) * 1024 + k0 + schunk, &Bsm[buf][(i * 4 + wave) * 512]);
    }
  };

  stage(0, 0);

  for (int kb = 0; kb < 16; kb++){
    const int cur = kb & 1;
    if (kb < 15){
      stage(cur ^ 1, kb + 1);
      asm volatile("s_waitcnt vmcnt(8)" ::: "memory");
    } else {
      asm volatile("s_waitcnt vmcnt(0)" ::: "memory");
    }
    __builtin_amdgcn_s_barrier();
    __builtin_amdgcn_s_setprio(1);
#pragma unroll
    for (int ks = 0; ks < 2; ks++){
      s8v af[4], bfr[4];
#pragma unroll
      for (int f = 0; f < 4; f++){
        int ch = (((ks * 4 + l4) ^ (l15 & 7)) << 3);
        af[f]  = *reinterpret_cast<const s8v*>(&Asm[cur][(wr * 64 + f * 16 + l15) * 64 + ch]);
        bfr[f] = *reinterpret_cast<const s8v*>(&Bsm[cur][(wc * 64 + f * 16 + l15) * 64 + ch]);
      }
#pragma unroll
      for (int fr = 0; fr < 4; fr++)
#pragma unroll
        for (int fc = 0; fc < 4; fc++)
          acc[fr][fc] = __builtin_amdgcn_mfma_f32_16x16x32_bf16(af[fr], bfr[fc], acc[fr][fc], 0, 0, 0);
    }
    __builtin_amdgcn_s_setprio(0);
    __builtin_amdgcn_s_barrier();
  }

  // fused epilogue: cols [nb,nb+128) all in one part (1024 % 128 == 0)
  const int pnum = nb >> 10;
#pragma unroll
  for (int fr = 0; fr < 4; fr++){
    int row  = mb + wr * 64 + fr * 16 + l4 * 4;
    int b    = row >> 11;
    int nseq = row & 2047;
#pragma unroll
    for (int fc = 0; fc < 4; fc++){
      int col = nb + wc * 64 + fc * 16 + l15;
      int rem = col & 1023;
      int h = rem >> 6, d = rem & 63;
      int bh = b * 16 + h;
      if (pnum == 0){          // Q (scale pre-folded into W)
        size_t base = ((size_t)bh * SEQ + nseq) * 64 + d;
#pragma unroll
        for (int r = 0; r < 4; r++)
          Qh[base + (size_t)r * 64] = f2bf(acc[fr][fc][r]);
      } else if (pnum == 1){   // K
        size_t base = ((size_t)bh * SEQ + nseq) * 64 + d;
#pragma unroll
        for (int r = 0; r < 4; r++)
          Kh[base + (size_t)r * 64] = f2bf(acc[fr][fc][r]);
      } else {                 // V: transposed [bh][d][SEQ]
        size_t base = ((size_t)bh * 64 + d) * SEQ + nseq;
        *reinterpret_cast<ushort4*>(&Vth[base]) =
            make_ushort4(f2bf(acc[fr][fc][0]), f2bf(acc[fr][fc][1]),
                         f2bf(acc[fr][fc][2]), f2bf(acc[fr][fc][3]));
      }
    }
  }
}

// ---------------- out-projection GEMM (plain bf16, dbuf + swizzle) ----------------
__global__ __launch_bounds__(256, 2) void k_gemm_out(
    const ushort_t* __restrict__ Ah, const ushort_t* __restrict__ Bth,
    float* __restrict__ C, const float* __restrict__ bias){
  __shared__ __align__(16) ushort_t Asm[2][GBM * GBK];
  __shared__ __align__(16) ushort_t Bsm[2][GBM * GBK];
  const int tid  = threadIdx.x;
  const int wave = tid >> 6, lane = tid & 63;
  const int mb = blockIdx.y * GBM, nb = blockIdx.x * GBN;
  const int wr = wave >> 1, wc = wave & 1;
  const int l15 = lane & 15, l4 = lane >> 4;
  const int rsub = lane >> 3;
  const int schunk = ((lane & 7) ^ rsub) * 8;
  f32x4 acc[4][4] = {};

  auto stage = [&](int buf, int kb){
    int k0 = kb * GBK;
#pragma unroll
    for (int i = 0; i < 4; i++){
      int row = (i * 4 + wave) * 8 + rsub;
      g2l16(Ah  + (size_t)(mb + row) * 1024 + k0 + schunk, &Asm[buf][(i * 4 + wave) * 512]);
      g2l16(Bth + (size_t)(nb + row) * 1024 + k0 + schunk, &Bsm[buf][(i * 4 + wave) * 512]);
    }
  };

  stage(0, 0);

  for (int kb = 0; kb < 16; kb++){
    const int cur = kb & 1;
    if (kb < 15){
      stage(cur ^ 1, kb + 1);
      asm volatile("s_waitcnt vmcnt(8)" ::: "memory");
    } else {
      asm volatile("s_waitcnt vmcnt(0)" ::: "memory");
    }
    __builtin_amdgcn_s_barrier();
    __builtin_amdgcn_s_setprio(1);
#pragma unroll
    for (int ks = 0; ks < 2; ks++){
      s8v af[4], bfr[4];
#pragma unroll
      for (int f = 0; f < 4; f++){
        int ch = (((ks * 4 + l4) ^ (l15 & 7)) << 3);
        af[f]  = *reinterpret_cast<const s8v*>(&Asm[cur][(wr * 64 + f * 16 + l15) * 64 + ch]);
        bfr[f] = *reinterpret_cast<const s8v*>(&Bsm[cur][(wc * 64 + f * 16 + l15) * 64 + ch]);
      }
#pragma unroll
      for (int fr = 0; fr < 4; fr++)
#pragma unroll
        for (int fc = 0; fc < 4; fc++)
          acc[fr][fc] = __builtin_amdgcn_mfma_f32_16x16x32_bf16(af[fr], bfr[fc], acc[fr][fc], 0, 0, 0);
    }
    __builtin_amdgcn_s_setprio(0);
    __builtin_amdgcn_s_barrier();
  }
#pragma unroll
  for (int fr = 0; fr < 4; fr++){
    int row = mb + wr * 64 + fr * 16 + l4 * 4;
#pragma unroll
    for (int fc = 0; fc < 4; fc++){
      int col = nb + wc * 64 + fc * 16 + l15;
      float bv = bias[col];
#pragma unroll
      for (int r = 0; r < 4; r++)
        C[(size_t)(row + r) * 1024 + col] = acc[fr][fc][r] + bv;
    }
  }
}

// ---------------- flash attention (r12 base + MFMA-lsum + fzero hoist) ----------------
// Grid 512 x 256 (4 waves x 32 q = 128 q/block), LDS 32KB (K+V dbuf, NO P buffer).
// Swapped 32x32 QK -> C[kv][q]; in-register P via cvt_pk + v_permlane32_swap.
// NEW vs r12: (a) lsum computed by ONE extra MFMA accumulator o_l = P x ones
//   (4 MFMAs/iter on the idle matrix pipe) -- kills 32 VALU adds/iter AND the
//   epilogue cross-lane reduce+shuffles (o_l[r] indexes exactly like o0[r]);
// (b) QK accumulators start from hoisted fzero via first-step C-in (kills 64
//   v_mov/iter). Denominator sums the SAME bf16-rounded P as the numerator.
__global__ __launch_bounds__(256, 2) void k_flash(
    const ushort_t* __restrict__ Qh, const ushort_t* __restrict__ Kh,
    const ushort_t* __restrict__ Vth, ushort_t* __restrict__ Ah){
  __shared__ __align__(16) ushort_t KhS[2][64 * 64];   // [kv][d]
  __shared__ __align__(16) ushort_t VhS[2][64 * 64];   // [d][kv]
  const int lid = blockIdx.x;             // 0..511
  const int xcd = lid & 7, g = lid >> 3;  // 8 XCDs x 64 blocks
  const int bh = xcd * 4 + (g & 3);       // each XCD owns 4 heads (K/V L2-resident)
  const int qb = (g >> 2) * 128;
  const int tid = threadIdx.x, wave = tid >> 6, lane = tid & 63;
  const int l31 = lane & 31, hh = lane >> 5;
  const int b = bh >> 4, hd = bh & 15;
  const size_t hbase = (size_t)bh * SEQ * 64;
  const int rsub = lane >> 3;             // 0..7
  const int schunk = ((lane & 7) ^ rsub) * 8;

  // frag-read element offsets: row l31, chunk (2s+hh) ^ (l31&7)
  int fch[4];
#pragma unroll
  for (int s = 0; s < 4; s++)
    fch[s] = (((2 * s + hh) ^ (l31 & 7)) << 3);
  const int fbase = l31 * 64;

  // Q as B-operand frags: lane(q=l31, hh) holds Q[q][d = 16s + 8hh + 0..7]
  s8v qf[4];
#pragma unroll
  for (int s = 0; s < 4; s++)
    qf[s] = *reinterpret_cast<const s8v*>(
        &Qh[hbase + (size_t)(qb + wave * 32 + l31) * 64 + s * 16 + hh * 8]);

  // all-ones bf16 B-operand fragment (layout-independent: every element 1.0)
  s8v onesv;
#pragma unroll
  for (int j = 0; j < 8; j++) onesv[j] = (short)0x3F80;

  const f32x16 fzero = {};
  f32x16 o0 = {}, o1 = {};   // O[q][d 0..31], O[q][d 32..63]
  f32x16 o_l = {};           // lsum[q] replicated across cols (P x ones)

  auto stage = [&](int buf, int kt){
    int kvb = kt * 64;
#pragma unroll
    for (int i = 0; i < 2; i++){
      int row = (i * 4 + wave) * 8 + rsub;
      g2l16(Kh  + hbase + (size_t)(kvb + row) * 64 + schunk, &KhS[buf][(i * 4 + wave) * 512]);
      g2l16(Vth + ((size_t)bh * 64 + row) * SEQ + kvb + schunk, &VhS[buf][(i * 4 + wave) * 512]);
    }
  };

  stage(0, 0);

  for (int kt = 0; kt < 32; kt++){
    const int cur = kt & 1;
    if (kt < 31){
      stage(cur ^ 1, kt + 1);                          // next tile's 4 loads in flight
      asm volatile("s_waitcnt vmcnt(4)" ::: "memory"); // current tile's 4 landed
    } else {
      asm volatile("s_waitcnt vmcnt(0)" ::: "memory");
    }
    __builtin_amdgcn_s_barrier();

    // QK: C[kv][q], two 32-kv row blocks, K-dim = 64 d in 4 steps (fzero C-in)
    __builtin_amdgcn_s_setprio(1);
    s8v kf0 = *reinterpret_cast<const s8v*>(&KhS[cur][fbase + fch[0]]);
    s8v kg0 = *reinterpret_cast<const s8v*>(&KhS[cur][fbase + 2048 + fch[0]]);
    f32x16 s0 = __builtin_amdgcn_mfma_f32_32x32x16_bf16(kf0, qf[0], fzero, 0, 0, 0);
    f32x16 s1 = __builtin_amdgcn_mfma_f32_32x32x16_bf16(kg0, qf[0], fzero, 0, 0, 0);
#pragma unroll
    for (int s = 1; s < 4; s++){
      s8v kf = *reinterpret_cast<const s8v*>(&KhS[cur][fbase + fch[s]]);
      s8v kg = *reinterpret_cast<const s8v*>(&KhS[cur][fbase + 2048 + fch[s]]);
      s0 = __builtin_amdgcn_mfma_f32_32x32x16_bf16(kf, qf[s], s0, 0, 0, 0);
      s1 = __builtin_amdgcn_mfma_f32_32x32x16_bf16(kg, qf[s], s1, 0, 0, 0);
    }
    __builtin_amdgcn_s_setprio(0);

    // fixed-max softmax + pack (no scalar lsum adds)
    uint32 w[2][8];
#pragma unroll
    for (int t = 0; t < 8; t++){
      float pa = __builtin_amdgcn_exp2f(s0[2 * t]     - MFIX);
      float pb = __builtin_amdgcn_exp2f(s0[2 * t + 1] - MFIX);
      w[0][t] = cvt_pk_bf16(pa, pb);
    }
#pragma unroll
    for (int t = 0; t < 8; t++){
      float pa = __builtin_amdgcn_exp2f(s1[2 * t]     - MFIX);
      float pb = __builtin_amdgcn_exp2f(s1[2 * t + 1] - MFIX);
      w[1][t] = cvt_pk_bf16(pa, pb);
    }

    // PV: O[q][d] += P[32q x 16kv] . V[16kv x 32d]; lsum via P x ones MFMA
    __builtin_amdgcn_s_setprio(1);
#pragma unroll
    for (int s = 0; s < 4; s++){
      const int rb = s >> 1, u = (s & 1) * 4;
      uint32 m0 = w[rb][u],     m2 = w[rb][u + 2];
      uint32 m1 = w[rb][u + 1], m3 = w[rb][u + 3];
      asm("v_permlane32_swap_b32 %0, %1" : "+v"(m0), "+v"(m2));
      asm("v_permlane32_swap_b32 %0, %1" : "+v"(m1), "+v"(m3));
      union { uint32 u4[4]; s8v v; } pf;
      pf.u4[0] = m0; pf.u4[1] = m1; pf.u4[2] = m2; pf.u4[3] = m3;
      s8v vf0 = *reinterpret_cast<const s8v*>(&VhS[cur][fbase + fch[s]]);
      s8v vf1 = *reinterpret_cast<const s8v*>(&VhS[cur][fbase + 2048 + fch[s]]);
      o0  = __builtin_amdgcn_mfma_f32_32x32x16_bf16(pf.v, vf0,   o0,  0, 0, 0);
      o1  = __builtin_amdgcn_mfma_f32_32x32x16_bf16(pf.v, vf1,   o1,  0, 0, 0);
      o_l = __builtin_amdgcn_mfma_f32_32x32x16_bf16(pf.v, onesv, o_l, 0, 0, 0);
    }
    __builtin_amdgcn_s_setprio(0);
    __builtin_amdgcn_s_barrier();   // all waves done reading cur buffers
  }

  // epilogue: o_l[r] = lsum for the SAME q as o0[r]/o1[r] -> no shuffles
#pragma unroll
  for (int r = 0; r < 16; r++){
    float sc = 1.f / o_l[r];
    int q = (r & 3) + 8 * (r >> 2) + 4 * hh;
    int n = qb + wave * 32 + q;
    size_t rowb = (size_t)(b * SEQ + n) * 1024 + hd * 64;
    Ah[rowb + l31]      = f2bf(o0[r] * sc);
    Ah[rowb + 32 + l31] = f2bf(o1[r] * sc);
  }
}

// ---------------- host launch ----------------
extern "C" void kernel_launch(void* const* d_in, const int* in_sizes, int n_in,
                              void* d_out, int out_size, void* d_ws, size_t ws_size,
                              hipStream_t stream){
  const float* x     = (const float*)d_in[0];
  const float* w_qkv = (const float*)d_in[1];
  const float* w_out = (const float*)d_in[2];
  const float* b_out = (const float*)d_in[3];
  float* out = (float*)d_out;
  char* ws = (char*)d_ws;

  ushort_t* Xh    = (ushort_t*)(ws);                      //  8 MB
  ushort_t* Wqt_h = (ushort_t*)(ws + 8388608);            //  6 MB
  ushort_t* Wot_h = (ushort_t*)(ws + 14680064);           //  2 MB
  ushort_t* Qh    = (ushort_t*)(ws + 16777216);           //  8 MB
  ushort_t* Kh    = (ushort_t*)(ws + 25165824);           //  8 MB
  ushort_t* Vth   = (ushort_t*)(ws + 33554432);           //  8 MB
  ushort_t* Ah    = (ushort_t*)(ws + 41943040);           //  8 MB

  // 1. fused prep: x -> Xh; w_qkv -> Wqt_h (T, Q cols pre-scaled); w_out -> Wot_h (T)
  k_prep<<<5120, 256, 0, stream>>>(x, w_qkv, w_out, Xh, Wqt_h, Wot_h);
  // 2. QKV projection with fused per-head epilogue
  k_gemm_qkv<<<dim3(24, 32), 256, 0, stream>>>(Xh, Wqt_h, Qh, Kh, Vth);
  // 3. attention -> Ah (bf16)
  k_flash<<<512, 256, 0, stream>>>(Qh, Kh, Vth, Ah);
  // 4. out = Ah @ Wot + b_out
  k_gemm_out<<<dim3(8, 32), 256, 0, stream>>>(Ah, Wot_h, out, b_out);
}